// Round 13
// baseline (210.396 us; speedup 1.0000x reference)
//
#include <hip/hip_runtime.h>
#include <hip/hip_bf16.h>
#include <math.h>
#include <stdint.h>

#define B 2
#define H 16
#define L 2048
#define D 64
#define NB 32

typedef unsigned short u16;
typedef unsigned int u32;
typedef __attribute__((ext_vector_type(2))) unsigned int u32x2;
typedef __attribute__((ext_vector_type(4))) unsigned int u32x4;
typedef __attribute__((ext_vector_type(8))) short s16x8;
typedef __attribute__((ext_vector_type(4))) float f32x4;

union FragU { s16x8 v; u32 u[4]; };

#if defined(__has_builtin)
#if __has_builtin(__builtin_amdgcn_exp2f)
#define EXP2F __builtin_amdgcn_exp2f
#else
#define EXP2F exp2f
#endif
#else
#define EXP2F exp2f
#endif
#define LOG2E 1.4426950408889634f
#define C1SC 0.18033688011112042f   // 0.125 * log2(e)

__device__ __forceinline__ u32 pkbf(float a, float b) {
  __hip_bfloat162 h = __float22bfloat162_rn(make_float2(a, b));  // v_cvt_pk_bf16_f32
  union { __hip_bfloat162 h; u32 u; } cv; cv.h = h; return cv.u;
}
__device__ __forceinline__ float bf2f(u32 u16bits) {
  union { u32 u; float f; } c; c.u = u16bits << 16; return c.f;
}
// split float4 -> packed hi (u32x2) + lo (u32x2), RNE both levels
__device__ __forceinline__ void split4(float4 p, u32x2& hi, u32x2& lo) {
  u32 h01 = pkbf(p.x, p.y), h23 = pkbf(p.z, p.w);
  float rx = p.x - bf2f(h01 & 0xffffu);
  float ry = p.y - bf2f(h01 >> 16);
  float rz = p.z - bf2f(h23 & 0xffffu);
  float rw = p.w - bf2f(h23 >> 16);
  hi = (u32x2){h01, h23};
  lo = (u32x2){pkbf(rx, ry), pkbf(rz, rw)};
}
// XOR-swizzled byte offset in a [64][128B] tile: 2 lanes/bank (free) for the
// fixed-col/varying-row ds_read_b128 / 8B-store pattern (guide §6 G4).
__device__ __forceinline__ int swz(int row, int colb) {
  return (row << 7) + (colb ^ ((row & 7) << 4));
}

// ---------------------------------------------------------------------------
// k_prep: single pass over K (split + column sums fused), V transpose split.
// XCD-ALIGNED task map: task (bh,j) runs on XCD bh>>2 — the same XCD whose
// k_attn WGs consume bh's planes.
// ---------------------------------------------------------------------------
__global__ __launch_bounds__(256) void k_prep(const float* __restrict__ k,
                                              const float* __restrict__ v,
                                              float* __restrict__ ksum,
                                              u16* __restrict__ khi_g,
                                              u16* __restrict__ klo_g,
                                              u16* __restrict__ vthi_g,
                                              u16* __restrict__ vtlo_g,
                                              float* __restrict__ kbmax) {
  int blk0 = blockIdx.x, t = threadIdx.x;
  int xcd = blk0 & 7, sidx = blk0 >> 3;        // HW: XCD = blockIdx % 8
  int bh = xcd * 4 + (sidx >> 5), j = sidx & 31;
  int blk = bh * 32 + j;                       // bijective remap
  int lane = t & 63, w = t >> 6;
  __shared__ float vt[64 * 65];
  __shared__ float pk_[4][64];
  __shared__ unsigned bmaxS;
  if (t == 0) bmaxS = 0u;
  size_t base = (size_t)blk * 4096;

  int r0 = t >> 3;          // 0..31
  int c8 = (t & 7) * 8;     // 0..56
  float cs[8] = {0.f, 0.f, 0.f, 0.f, 0.f, 0.f, 0.f, 0.f};
  float rmax = 0.f;
#pragma unroll
  for (int it = 0; it < 2; ++it) {
    int r = r0 + 32 * it;
    const float* kp = k + base + r * 64 + c8;
    float4 f0 = *(const float4*)kp;
    float4 f1 = *(const float4*)(kp + 4);
    u32x2 h0, l0, h1, l1;
    split4(f0, h0, l0); split4(f1, h1, l1);
    *(u32x4*)(khi_g + base + r * 64 + c8) = (u32x4){h0[0], h0[1], h1[0], h1[1]};
    *(u32x4*)(klo_g + base + r * 64 + c8) = (u32x4){l0[0], l0[1], l1[0], l1[1]};
    cs[0] += f0.x; cs[1] += f0.y; cs[2] += f0.z; cs[3] += f0.w;
    cs[4] += f1.x; cs[5] += f1.y; cs[6] += f1.z; cs[7] += f1.w;
    float ssq = f0.x*f0.x + f0.y*f0.y + f0.z*f0.z + f0.w*f0.w
              + f1.x*f1.x + f1.y*f1.y + f1.z*f1.z + f1.w*f1.w;
    ssq += __shfl_xor(ssq, 1); ssq += __shfl_xor(ssq, 2); ssq += __shfl_xor(ssq, 4);
    if ((t & 7) == 0) rmax = fmaxf(rmax, ssq);
    const float* vp = v + base + r * 64 + c8;
    float4 g0 = *(const float4*)vp;
    float4 g1 = *(const float4*)(vp + 4);
    vt[(c8 + 0) * 65 + r] = g0.x;
    vt[(c8 + 1) * 65 + r] = g0.y;
    vt[(c8 + 2) * 65 + r] = g0.z;
    vt[(c8 + 3) * 65 + r] = g0.w;
    vt[(c8 + 4) * 65 + r] = g1.x;
    vt[(c8 + 5) * 65 + r] = g1.y;
    vt[(c8 + 6) * 65 + r] = g1.z;
    vt[(c8 + 7) * 65 + r] = g1.w;
  }
  if ((t & 7) == 0) atomicMax(&bmaxS, __float_as_uint(rmax));
  // column-sum reduce over r-groups: xor 8/16/32 keep lane&7 (the column group)
#pragma unroll
  for (int i = 0; i < 8; ++i) {
    cs[i] += __shfl_xor(cs[i], 8);
    cs[i] += __shfl_xor(cs[i], 16);
    cs[i] += __shfl_xor(cs[i], 32);
  }
  if (lane < 8) {
    *(float4*)&pk_[w][lane * 8]     = (float4){cs[0], cs[1], cs[2], cs[3]};
    *(float4*)&pk_[w][lane * 8 + 4] = (float4){cs[4], cs[5], cs[6], cs[7]};
  }
  __syncthreads();
  if (t < 64) ksum[(size_t)blk * 64 + t] = pk_[0][t] + pk_[1][t] + pk_[2][t] + pk_[3][t];
  if (t == 0) kbmax[blk] = __uint_as_float(bmaxS);
#pragma unroll
  for (int it = 0; it < 2; ++it) {
    int idx = t + 256 * it, d = idx >> 3, s8 = (idx & 7) * 8;
    const float* vr = &vt[d * 65 + s8];
    float4 f0 = {vr[0], vr[1], vr[2], vr[3]};
    float4 f1 = {vr[4], vr[5], vr[6], vr[7]};
    u32x2 h0, l0, h1, l1;
    split4(f0, h0, l0); split4(f1, h1, l1);
    size_t o = (size_t)bh * 131072 + (size_t)d * 2048 + j * 64 + s8;
    *(u32x4*)(vthi_g + o) = (u32x4){h0[0], h0[1], h1[0], h1[1]};
    *(u32x4*)(vtlo_g + o) = (u32x4){l0[0], l0[1], l1[0], l1[1]};
  }
}

// ---------------------------------------------------------------------------
// k_attn: ONE q-block per WG (1024 WGs, 2 resident/CU + 512 queued -> load
// balancing; finish-tail halves vs all-resident 512-grid). Body is the R11
// j-loop verbatim minus the qb dimension: waves split K-rows, Q in regs,
// XOR-swizzled P dbuf (1 barrier/j), K prefetch, early V, exp2 softmax,
// nontemporal O. LDS 32.8 KB; launch_bounds(256,2).
// R12 crash root cause: grid was B*H*NB*2 = 2048 (should be 1024 tasks) ->
// swizzle produced bh up to 35 -> OOB. Fixed: grid = B*H*NB = 1024.
// LDS map (bytes), total 32800:
//   P planes: buf0 hi @0, buf0 lo @8192, buf1 hi @16384, buf1 lo @24576
//   overlay (dead before Pass B, inside buf0): rbm u32[64*33] @0 (8448),
//     lpart f32[4][64] @8448, qm @9472, MS @9728, linv @9984
//   flg @32768
// ---------------------------------------------------------------------------
__global__ __launch_bounds__(256, 2) void k_attn(
    const float* __restrict__ q,
    const float* __restrict__ ksum,
    const u16* __restrict__ khi_g, const u16* __restrict__ klo_g,
    const u16* __restrict__ vthi_g, const u16* __restrict__ vtlo_g,
    const float* __restrict__ cdfthreshd, const float* __restrict__ simthreshd1,
    const float* __restrict__ pvthreshd, const float* __restrict__ kbmax,
    float* __restrict__ out) {
  int blk0 = blockIdx.x;
  int blk = (blk0 & 7) * 128 + (blk0 >> 3);   // bijective for blk0 in [0,1024)
  int bh = blk >> 5, iq = blk & 31, h = bh & (H - 1);
  int t = threadIdx.x, lane = t & 63, w = t >> 6;
  int m16 = lane & 15, quad = lane >> 4;

  __shared__ __align__(16) uint8_t smem[32800];
  u32*   rbm   = (u32*)smem;                    // overlay: [64][33] keys
  float* lpart = (float*)(smem + 8448);         // [4][64]
  float* qmS   = (float*)(smem + 9472);         // [64]
  float* MSs   = (float*)(smem + 9728);         // [64]
  float* linvS = (float*)(smem + 9984);         // [64]
  int*   flg   = (int*)(smem + 32768);          // [0]=pooled [1]=mw [2]=gm [3]=kmax2
#define PHB(b) (smem + (b) * 16384)
#define PLB(b) (smem + (b) * 16384 + 8192)

  const float* qg = q + ((size_t)bh * L + (size_t)iq * 64) * D;
  const u16* kh = khi_g + (size_t)bh * (L * D);
  const u16* kl = klo_g + (size_t)bh * (L * D);
  const u16* vh = vthi_g + (size_t)bh * (L * D);
  const u16* vl = vtlo_g + (size_t)bh * (L * D);

  // ---- Q B-fragments from global (f32 -> split, registers) ----
  s16x8 qhf[4][2], qlf[4][2];
#pragma unroll
  for (int nt = 0; nt < 4; ++nt)
#pragma unroll
    for (int ks = 0; ks < 2; ++ks) {
      const float* p0 = qg + (16 * nt + m16) * 64 + ks * 32 + quad * 8;
      float4 a = *(const float4*)p0;
      float4 b2 = *(const float4*)(p0 + 4);
      u32x2 ha, la, hb, lb;
      split4(a, ha, la); split4(b2, hb, lb);
      FragU fh, fl;
      fh.u[0] = ha[0]; fh.u[1] = ha[1]; fh.u[2] = hb[0]; fh.u[3] = hb[1];
      fl.u[0] = la[0]; fl.u[1] = la[1]; fl.u[2] = lb[0]; fl.u[3] = lb[1];
      qhf[nt][ks] = fh.v; qlf[nt][ks] = fl.v;
    }
  for (int e = t; e < 64 * 33; e += 256) rbm[e] = 0x7F800000u;

  // ---- phase 1: qm (w0), kmax2 (w1) ----
  if (w == 0) {
    float s = 0.f;
    for (int r = 0; r < 64; ++r) s += qg[r * 64 + lane];
    qmS[lane] = s * (1.f / 64.f);
  }
  if (w == 1) {
    float m = (lane < 32) ? kbmax[bh * 32 + lane] : 0.f;
    for (int off = 16; off; off >>= 1) m = fmaxf(m, __shfl_xor(m, off, 32));
    if (lane == 0) ((float*)flg)[3] = m;
  }
  __syncthreads();

  // ---- phase 2: CDF keep (w0); pooled cos + M (w1) ----
  bool keepj = false;
  if (w == 0 && lane < 32) {
    int j = lane;
    const float* ksp = ksum + (size_t)bh * NB * 64 + j * 64;
    float sv = 0.f;
    for (int d = 0; d < 64; ++d) sv += qmS[d] * ksp[d];
    sv *= (1.f / 64.f) * 0.125f;
    float mx = sv;
    for (int off = 16; off; off >>= 1) mx = fmaxf(mx, __shfl_xor(mx, off, 32));
    float p = expf(sv - mx);
    float sum = p;
    for (int off = 16; off; off >>= 1) sum += __shfl_xor(sum, off, 32);
    p /= sum;
    float excl = 0.f;
    for (int u = 0; u < 32; ++u) {
      float pu = __shfl(p, u, 32);
      if ((pu > p) || (pu == p && u < j)) excl += pu;
    }
    keepj = excl < cdfthreshd[h];
  }
  if (w == 1) {
    int r = lane;
    float kmax2 = ((float*)flg)[3];
    float dot = 0.f, qn2 = 0.f, qmn2 = 0.f;
    for (int d = 0; d < 64; ++d) {
      float a = qg[r * 64 + d], b2 = qmS[d];
      dot += a * b2; qn2 += a * a; qmn2 += b2 * b2;
    }
    float cs = dot / (sqrtf(qn2) * sqrtf(qmn2) + 1e-6f);
    float su = cs;
    for (int off = 32; off; off >>= 1) su += __shfl_xor(su, off);
    if (lane == 0) flg[0] = (su * (1.f / 64.f)) > simthreshd1[h];
    MSs[r] = sqrtf(qn2 * kmax2) * 0.125f;  // M_r >= |s| (Cauchy-Schwarz)
  }
  __syncthreads();
  if (w == 0 && lane < 32) {
    bool bit = keepj || !flg[0] || (lane == 0);
    unsigned long long bal = __ballot(bit);
    if (lane == 0) flg[1] = (int)(u32)bal;
  }
  __syncthreads();
  u32 mw = (u32)flg[1];

  // Mq in LOG2 domain (rbm keys / lse / gate all consistently log2)
  float Mq[4];
#pragma unroll
  for (int nt = 0; nt < 4; ++nt) Mq[nt] = MSs[16 * nt + m16] * LOG2E;

  // ---- Pass A: wave w owns K-rows 16w..16w+15; K prefetched across j ----
  float lp[4] = {0.f, 0.f, 0.f, 0.f};
  {
    u32 rm = mw;
    int j = (int)__builtin_ctz(rm); rm &= rm - 1;
    s16x8 ka0[2], ka1[2];
    {
      const u16* kr0 = kh + (size_t)(j * 64 + 16 * w + m16) * 64 + quad * 8;
      const u16* kl0 = kl + (size_t)(j * 64 + 16 * w + m16) * 64 + quad * 8;
#pragma unroll
      for (int ks = 0; ks < 2; ++ks) {
        ka0[ks] = *(const s16x8*)(kr0 + ks * 32);
        ka1[ks] = *(const s16x8*)(kl0 + ks * 32);
      }
    }
    for (;;) {
      f32x4 acc[4];
#pragma unroll
      for (int nt = 0; nt < 4; ++nt) acc[nt] = (f32x4){0.f, 0.f, 0.f, 0.f};
      __builtin_amdgcn_s_setprio(1);
#pragma unroll
      for (int ks = 0; ks < 2; ++ks)
#pragma unroll
        for (int nt = 0; nt < 4; ++nt) {
          acc[nt] = __builtin_amdgcn_mfma_f32_16x16x32_bf16(ka0[ks], qhf[nt][ks], acc[nt], 0, 0, 0);
          acc[nt] = __builtin_amdgcn_mfma_f32_16x16x32_bf16(ka1[ks], qhf[nt][ks], acc[nt], 0, 0, 0);
          acc[nt] = __builtin_amdgcn_mfma_f32_16x16x32_bf16(ka0[ks], qlf[nt][ks], acc[nt], 0, 0, 0);
        }
      __builtin_amdgcn_s_setprio(0);
      // prefetch next-j K while exp/reductions run
      int nj = -1;
      s16x8 kn0[2], kn1[2];
      if (rm) {
        nj = (int)__builtin_ctz(rm); rm &= rm - 1;
        const u16* nr = kh + (size_t)(nj * 64 + 16 * w + m16) * 64 + quad * 8;
        const u16* nl = kl + (size_t)(nj * 64 + 16 * w + m16) * 64 + quad * 8;
#pragma unroll
        for (int ks = 0; ks < 2; ++ks) {
          kn0[ks] = *(const s16x8*)(nr + ks * 32);
          kn1[ks] = *(const s16x8*)(nl + ks * 32);
        }
      }
#pragma unroll
      for (int nt = 0; nt < 4; ++nt) {
        float vmax = -1e30f;
#pragma unroll
        for (int reg = 0; reg < 4; ++reg) {
          float s = fmaf(acc[nt][reg], C1SC, -Mq[nt]);   // log2 domain
          lp[nt] += EXP2F(s);
          vmax = fmaxf(vmax, s);
        }
        vmax = fmaxf(vmax, __shfl_xor(vmax, 16));
        vmax = fmaxf(vmax, __shfl_xor(vmax, 32));
        if (quad == 0)
          atomicMin(rbm + (16 * nt + m16) * 33 + j, __float_as_uint(fmaxf(-vmax, 0.f)));
      }
      if (nj < 0) break;
#pragma unroll
      for (int ks = 0; ks < 2; ++ks) { ka0[ks] = kn0[ks]; ka1[ks] = kn1[ks]; }
      j = nj;
    }
  }
#pragma unroll
  for (int nt = 0; nt < 4; ++nt) {
    float s = lp[nt];
    s += __shfl_xor(s, 16); s += __shfl_xor(s, 32);
    if (quad == 0) lpart[w * 64 + 16 * nt + m16] = s;
  }
  __syncthreads();
  if (t < 64) linvS[t] = 1.f / (lpart[t] + lpart[64 + t] + lpart[128 + t] + lpart[192 + t]);
  __syncthreads();

  // ---- PV gate (w0, keys in log2 domain) ----
  if (w == 0 && lane < 32) {
    bool keep = (mw >> lane) & 1u;
    if (keep && lane != 0) {
      float thr = pvthreshd[h] * 1e-3f;
      float mp = 0.f;
      for (int r = 0; r < 64; ++r) {
        float key = __uint_as_float(rbm[r * 33 + lane]);
        mp = fmaxf(mp, EXP2F(-key) * linvS[r]);
      }
      keep = mp >= thr;
    }
    unsigned long long bal = __ballot(keep);
    if (lane == 0) flg[2] = (int)(u32)bal;
  }
  __syncthreads();
  u32 gm = (u32)flg[2];

  float linq[4];
#pragma unroll
  for (int nt = 0; nt < 4; ++nt) linq[nt] = linvS[16 * nt + m16];
  f32x4 oacc[4];
#pragma unroll
  for (int nt = 0; nt < 4; ++nt) oacc[nt] = (f32x4){0.f, 0.f, 0.f, 0.f};
  __syncthreads();   // overlay (rbm/linv) reads complete before first P write

  // ---- Pass B: double-buffered P, ONE barrier per j ----
  {
    u32 rg = gm;
    int j = (int)__builtin_ctz(rg); rg &= rg - 1;   // sink bit 0 always set
    int buf = 0;
    s16x8 ka0[2], ka1[2];
    {
      const u16* kr0 = kh + (size_t)(j * 64 + 16 * w + m16) * 64 + quad * 8;
      const u16* kl0 = kl + (size_t)(j * 64 + 16 * w + m16) * 64 + quad * 8;
#pragma unroll
      for (int ks = 0; ks < 2; ++ks) {
        ka0[ks] = *(const s16x8*)(kr0 + ks * 32);
        ka1[ks] = *(const s16x8*)(kl0 + ks * 32);
      }
    }
    for (;;) {
      // V^T A-frags for current j (issued early, consumed after the barrier)
      s16x8 va0[2], va1[2];
      {
        const u16* vr0 = vh + (size_t)(16 * w + m16) * L + j * 64 + quad * 8;
        const u16* vl0 = vl + (size_t)(16 * w + m16) * L + j * 64 + quad * 8;
#pragma unroll
        for (int ks = 0; ks < 2; ++ks) {
          va0[ks] = *(const s16x8*)(vr0 + ks * 32);
          va1[ks] = *(const s16x8*)(vl0 + ks * 32);
        }
      }
      // S: wave's 16 K-rows x 64 q
      f32x4 acc[4];
#pragma unroll
      for (int nt = 0; nt < 4; ++nt) acc[nt] = (f32x4){0.f, 0.f, 0.f, 0.f};
      __builtin_amdgcn_s_setprio(1);
#pragma unroll
      for (int ks = 0; ks < 2; ++ks)
#pragma unroll
        for (int nt = 0; nt < 4; ++nt) {
          acc[nt] = __builtin_amdgcn_mfma_f32_16x16x32_bf16(ka0[ks], qhf[nt][ks], acc[nt], 0, 0, 0);
          acc[nt] = __builtin_amdgcn_mfma_f32_16x16x32_bf16(ka1[ks], qhf[nt][ks], acc[nt], 0, 0, 0);
          acc[nt] = __builtin_amdgcn_mfma_f32_16x16x32_bf16(ka0[ks], qlf[nt][ks], acc[nt], 0, 0, 0);
        }
      __builtin_amdgcn_s_setprio(0);
      // P = exp2(fma(S,C1,-Mq)) * linq -> split -> swizzled P[buf]
#pragma unroll
      for (int nt = 0; nt < 4; ++nt) {
        float4 pv;
        pv.x = EXP2F(fmaf(acc[nt][0], C1SC, -Mq[nt])) * linq[nt];
        pv.y = EXP2F(fmaf(acc[nt][1], C1SC, -Mq[nt])) * linq[nt];
        pv.z = EXP2F(fmaf(acc[nt][2], C1SC, -Mq[nt])) * linq[nt];
        pv.w = EXP2F(fmaf(acc[nt][3], C1SC, -Mq[nt])) * linq[nt];
        u32x2 hi, lo; split4(pv, hi, lo);
        int off = swz(16 * nt + m16, 32 * w + 8 * quad);
        *(u32x2*)(PHB(buf) + off) = hi;
        *(u32x2*)(PLB(buf) + off) = lo;
      }
      // prefetch next K (ka fully consumed)
      int nj = -1;
      if (rg) {
        nj = (int)__builtin_ctz(rg); rg &= rg - 1;
        const u16* nr = kh + (size_t)(nj * 64 + 16 * w + m16) * 64 + quad * 8;
        const u16* nl = kl + (size_t)(nj * 64 + 16 * w + m16) * 64 + quad * 8;
#pragma unroll
        for (int ks = 0; ks < 2; ++ks) {
          ka0[ks] = *(const s16x8*)(nr + ks * 32);
          ka1[ks] = *(const s16x8*)(nl + ks * 32);
        }
      }
      __syncthreads();   // P[buf] complete (RAW); next iter writes buf^1
      // PV: A = V^T rows 16w..16w+15, B = P frags from LDS
      const uint8_t* ph_ = PHB(buf);
      const uint8_t* pl_ = PLB(buf);
#pragma unroll
      for (int ks = 0; ks < 2; ++ks)
#pragma unroll
        for (int nt = 0; nt < 4; ++nt) {
          s16x8 pbh = *(const s16x8*)(ph_ + swz(16 * nt + m16, ks * 64 + quad * 16));
          s16x8 pbl = *(const s16x8*)(pl_ + swz(16 * nt + m16, ks * 64 + quad * 16));
          __builtin_amdgcn_s_setprio(1);
          oacc[nt] = __builtin_amdgcn_mfma_f32_16x16x32_bf16(va0[ks], pbh, oacc[nt], 0, 0, 0);
          oacc[nt] = __builtin_amdgcn_mfma_f32_16x16x32_bf16(va1[ks], pbh, oacc[nt], 0, 0, 0);
          oacc[nt] = __builtin_amdgcn_mfma_f32_16x16x32_bf16(va0[ks], pbl, oacc[nt], 0, 0, 0);
          __builtin_amdgcn_s_setprio(0);
        }
      if (nj < 0) break;
      buf ^= 1;
      j = nj;
    }
  }

  // ---- store O (nontemporal): lane -> qrow = 16nt+m16, d = 16w+4quad ----
  float* ob = out + ((size_t)bh * L + (size_t)iq * 64) * D;
#pragma unroll
  for (int nt = 0; nt < 4; ++nt)
    __builtin_nontemporal_store(oacc[nt],
        (f32x4*)(ob + (16 * nt + m16) * 64 + 16 * w + 4 * quad));
}

// ---------------------------------------------------------------------------
extern "C" void kernel_launch(void* const* d_in, const int* in_sizes, int n_in,
                              void* d_out, int out_size, void* d_ws, size_t ws_size,
                              hipStream_t stream) {
  (void)in_sizes; (void)n_in; (void)out_size; (void)ws_size;
  const float* q   = (const float*)d_in[0];
  const float* k   = (const float*)d_in[1];
  const float* v   = (const float*)d_in[2];
  const float* cdf = (const float*)d_in[3];
  const float* sim = (const float*)d_in[4];
  const float* pvt = (const float*)d_in[5];
  float* out = (float*)d_out;

  uint8_t* w8 = (uint8_t*)d_ws;
  float* ksum  = (float*)w8;                          // 1024*64 f (256 KB)
  float* kbmax = (float*)(w8 + 262144);               // 1024 f (4 KB)
  u16* khi_g  = (u16*)(w8 + 266240);                  // 4 planes x 8 MB
  u16* klo_g  = khi_g + (size_t)B * H * L * D;
  u16* vthi_g = klo_g + (size_t)B * H * L * D;
  u16* vtlo_g = vthi_g + (size_t)B * H * L * D;

  k_prep<<<B * H * NB, 256, 0, stream>>>(k, v, ksum, khi_g, klo_g, vthi_g, vtlo_g, kbmax);
  k_attn<<<B * H * NB, 256, 0, stream>>>(q, ksum, khi_g, klo_g, vthi_g, vtlo_g,
                                         cdf, sim, pvt, kbmax, out);
}